// Round 8
// baseline (1114.893 us; speedup 1.0000x reference)
//
#include <hip/hip_runtime.h>
#include <hip/hip_bf16.h>

#define NBATCH 2
#define NBB    16
#define NIC    8
#define NOC    16
#define NQ     30
#define NMM    6
#define NU     5
#define NV     5
#define NNC    25   // NU*NV

// ---- block-uniform param loads (uniform addr -> scalar regs) ----
#define LOADT(u) const float pTre##u = pTau_re[qm * NU + u], pTim##u = pTau_im[qm * NU + u];
#define LOADS(v) const float pSre##v = pPsi_re[m * NV + v],  pSim##v = pPsi_im[m * NV + v];

// ---- v-basis, named scalars ----
#define EVv(v, PS)                                            \
    const float rr_##v  = __expf((PS) * pSre##v);             \
    const float evr##v  = rr_##v * __cosf((PS) * pSim##v);    \
    const float evi##v  = rr_##v * __sinf((PS) * pSim##v);

// ---- one (u,v) tap: 2 typed ds_read_b128 + 16 FMA-pairs ----
#define TAPV(u, v) {                                          \
    const float tr = gr * evr##v - gi * evi##v;               \
    const float ti = gr * evi##v + gi * evr##v;               \
    const float4 wA = Wp4[wb + (u * NV + v) * 8];             \
    const float4 wB = Wp4[wb + (u * NV + v) * 8 + 1];         \
    a0r += tr * wA.x - ti * wA.y;  a0i += tr * wA.y + ti * wA.x; \
    a1r += tr * wA.z - ti * wA.w;  a1i += tr * wA.w + ti * wA.z; \
    a2r += tr * wB.x - ti * wB.y;  a2i += tr * wB.y + ti * wB.x; \
    a3r += tr * wB.z - ti * wB.w;  a3i += tr * wB.w + ti * wB.z; }

#define TAPU(u, LT) {                                         \
    const float ru  = __expf((LT) * pTre##u);                 \
    const float eur = ru * __cosf((LT) * pTim##u);            \
    const float eui = ru * __sinf((LT) * pTim##u);            \
    const float gr  = Are * eur - Aim * eui;                  \
    const float gi  = Are * eui + Aim * eur;                  \
    TAPV(u, 0) TAPV(u, 1) TAPV(u, 2) TAPV(u, 3) TAPV(u, 4) }

// ---- full per-channel body; all inputs passed as named components ----
#define CBODY(c, XR, XI, LA, PH, LT, PS) {                    \
    const float ar  = (LA) * pAre + (PH) * pPre;              \
    const float ai  = (LA) * pAim + (PH) * pPim;              \
    const float ea  = __expf(ar);                             \
    const float er_ = ea * __cosf(ai), ei_ = ea * __sinf(ai); \
    const float Are = (XR) * er_ - (XI) * ei_;                \
    const float Aim = (XR) * ei_ + (XI) * er_;                \
    EVv(0, PS) EVv(1, PS) EVv(2, PS) EVv(3, PS) EVv(4, PS)    \
    const int wb = (c) * (NNC * 8) + og2;                     \
    TAPU(0, LT) TAPU(1, LT) TAPU(2, LT) TAPU(3, LT) TAPU(4, LT) }

__device__ __forceinline__ float2 wentry(const float* __restrict__ coeffs,
                                         int c, int n, int o) {
    if (n < 12)
        return make_float2(coeffs[(c * NNC + (23 - 2 * n)) * NOC + o],
                           coeffs[(c * NNC + (24 - 2 * n)) * NOC + o]);
    if (n == 12)
        return make_float2(coeffs[(c * NNC) * NOC + o], 0.0f);
    return make_float2(coeffs[(c * NNC + (2 * n - 25)) * NOC + o],
                       coeffs[(c * NNC + (2 * n - 24)) * NOC + o]);
}

__global__ __launch_bounds__(256, 3) void lbc_main(
    const float* __restrict__ x_re,   const float* __restrict__ x_im,
    const float* __restrict__ lnAlpha,const float* __restrict__ Phi,
    const float* __restrict__ lnTau,  const float* __restrict__ Psi,
    const float* __restrict__ pAlpha_re, const float* __restrict__ pAlpha_im,
    const float* __restrict__ pPhi_re,   const float* __restrict__ pPhi_im,
    const float* __restrict__ pTau_re,   const float* __restrict__ pTau_im,
    const float* __restrict__ pPsi_re,   const float* __restrict__ pPsi_im,
    const float* __restrict__ F_re,      const float* __restrict__ F_im,
    const float* __restrict__ coeffs,
    float* __restrict__ out)
{
    // Typed LDS: W'[c][n] = 8 float4 (16 complex o's), F folded in. 25.6 KiB.
    __shared__ float4 Wp4[NIC * NNC * 8];

    // Block identity: bid = ((b*NQ + q)*NMM + m)*4 + qt
    const int bid = blockIdx.x;
    const int qt  = bid & 3;
    const int bqm = bid >> 2;
    const int m   = bqm % NMM;
    const int q   = (bqm / NMM) % NQ;
    const int b   = bqm / (NMM * NQ);
    const int qm  = q * NMM + m;

    // ---- Stage W' into LDS (one float4 = 2 complex o's per slot) ----
    for (int idx = threadIdx.x; idx < NIC * NNC * 8; idx += 256) {
        const int op = idx & 7;                 // o-pair
        const int n  = (idx >> 3) % NNC;
        const int c  = idx / (NNC * 8);
        const float fr = F_re[qm * NNC + n];
        const float fi = F_im[qm * NNC + n];
        const float2 w0 = wentry(coeffs, c, n, 2 * op);
        const float2 w1 = wentry(coeffs, c, n, 2 * op + 1);
        Wp4[idx] = make_float4(w0.x * fr - w0.y * fi, w0.x * fi + w0.y * fr,
                               w1.x * fr - w1.y * fi, w1.x * fi + w1.y * fr);
    }
    __syncthreads();

    // ---- Thread identity: og = o-group (wave-uniform), p = point ----
    const int tid = threadIdx.x;
    const int og  = tid >> 6;                  // 0..3
    const int og2 = og * 2;
    const int p   = tid & 63;
    const int y   = qt * 4 + (p >> 4);
    const int x   = p & 15;
    const int pt  = (b * NBB + y) * NBB + x;

    // ---- Hoisted global loads: 12 contiguous float4 per thread ----
    const float4* xr4 = reinterpret_cast<const float4*>(x_re)    + pt * 2;
    const float4* xi4 = reinterpret_cast<const float4*>(x_im)    + pt * 2;
    const float4* la4 = reinterpret_cast<const float4*>(lnAlpha) + pt * 2;
    const float4* ph4 = reinterpret_cast<const float4*>(Phi)     + pt * 2;
    const float4* lt4 = reinterpret_cast<const float4*>(lnTau)   + pt * 2;
    const float4* ps4 = reinterpret_cast<const float4*>(Psi)     + pt * 2;
    const float4 xrA = xr4[0], xrB = xr4[1];
    const float4 xiA = xi4[0], xiB = xi4[1];
    const float4 laA = la4[0], laB = la4[1];
    const float4 phA = ph4[0], phB = ph4[1];
    const float4 ltA = lt4[0], ltB = lt4[1];
    const float4 psA = ps4[0], psB = ps4[1];

    // ---- Block-uniform basis params ----
    const float pAre = pAlpha_re[qm], pAim = pAlpha_im[qm];
    const float pPre = pPhi_re[m],    pPim = pPhi_im[m];
    LOADT(0) LOADT(1) LOADT(2) LOADT(3) LOADT(4)
    LOADS(0) LOADS(1) LOADS(2) LOADS(3) LOADS(4)

    // ---- Named scalar accumulators (o = og*4 .. og*4+3) ----
    float a0r = 0.f, a0i = 0.f, a1r = 0.f, a1i = 0.f;
    float a2r = 0.f, a2i = 0.f, a3r = 0.f, a3i = 0.f;

    CBODY(0, xrA.x, xiA.x, laA.x, phA.x, ltA.x, psA.x)
    CBODY(1, xrA.y, xiA.y, laA.y, phA.y, ltA.y, psA.y)
    CBODY(2, xrA.z, xiA.z, laA.z, phA.z, ltA.z, psA.z)
    CBODY(3, xrA.w, xiA.w, laA.w, phA.w, ltA.w, psA.w)
    CBODY(4, xrB.x, xiB.x, laB.x, phB.x, ltB.x, psB.x)
    CBODY(5, xrB.y, xiB.y, laB.y, phB.y, ltB.y, psB.y)
    CBODY(6, xrB.z, xiB.z, laB.z, phB.z, ltB.z, psB.z)
    CBODY(7, xrB.w, xiB.w, laB.w, phB.w, ltB.w, psB.w)

    // ---- Write out: [b, o, q, m, y, x, 2], o = og*4 .. og*4+3 ----
    float2* const o2 = reinterpret_cast<float2*>(out);
    const size_t stride_o = (size_t)NQ * NMM * NBB * NBB;   // 46080
    size_t oi = ((((size_t)b * NOC + og * 4) * NQ + q) * NMM + m) * (NBB * NBB)
                + y * NBB + x;
    o2[oi]                = make_float2(a0r, a0i);
    o2[oi +     stride_o] = make_float2(a1r, a1i);
    o2[oi + 2 * stride_o] = make_float2(a2r, a2i);
    o2[oi + 3 * stride_o] = make_float2(a3r, a3i);
}

extern "C" void kernel_launch(void* const* d_in, const int* in_sizes, int n_in,
                              void* d_out, int out_size, void* d_ws, size_t ws_size,
                              hipStream_t stream) {
    const float* x_re      = (const float*)d_in[0];
    const float* x_im      = (const float*)d_in[1];
    const float* lnAlpha   = (const float*)d_in[2];
    const float* Phi       = (const float*)d_in[3];
    const float* lnTau     = (const float*)d_in[4];
    const float* Psi       = (const float*)d_in[5];
    const float* pAlpha_re = (const float*)d_in[6];
    const float* pAlpha_im = (const float*)d_in[7];
    const float* pPhi_re   = (const float*)d_in[8];
    const float* pPhi_im   = (const float*)d_in[9];
    const float* pTau_re   = (const float*)d_in[10];
    const float* pTau_im   = (const float*)d_in[11];
    const float* pPsi_re   = (const float*)d_in[12];
    const float* pPsi_im   = (const float*)d_in[13];
    const float* F_re      = (const float*)d_in[14];
    const float* F_im      = (const float*)d_in[15];
    const float* coeffs    = (const float*)d_in[16];
    float* out = (float*)d_out;

    dim3 grid(NBATCH * NQ * NMM * 4);   // 1440: (b,q,m) x 4 quarter-tiles
    dim3 block(256);                    // 4 o-group waves x 64 points
    lbc_main<<<grid, block, 0, stream>>>(
        x_re, x_im, lnAlpha, Phi, lnTau, Psi,
        pAlpha_re, pAlpha_im, pPhi_re, pPhi_im,
        pTau_re, pTau_im, pPsi_re, pPsi_im,
        F_re, F_im, coeffs, out);
}

// Round 9
// 166.821 us; speedup vs baseline: 6.6832x; 6.6832x over previous
//
#include <hip/hip_runtime.h>
#include <hip/hip_bf16.h>

#define NBATCH 2
#define NBB    16
#define NIC    8
#define NOC    16
#define NQ     30
#define NMM    6
#define NU     5
#define NV     5
#define NNC    25   // NU*NV
#define OGR    4    // o-groups per block (wave-uniform)
#define OPG    4    // o's per group  (OGR*OPG == NOC)

__global__ __launch_bounds__(256, 4) void lbc_main(
    const float* __restrict__ x_re,   const float* __restrict__ x_im,
    const float* __restrict__ lnAlpha,const float* __restrict__ Phi,
    const float* __restrict__ lnTau,  const float* __restrict__ Psi,
    const float* __restrict__ pAlpha_re, const float* __restrict__ pAlpha_im,
    const float* __restrict__ pPhi_re,   const float* __restrict__ pPhi_im,
    const float* __restrict__ pTau_re,   const float* __restrict__ pTau_im,
    const float* __restrict__ pPsi_re,   const float* __restrict__ pPsi_im,
    const float* __restrict__ F_re,      const float* __restrict__ F_im,
    const float* __restrict__ coeffs,
    float* __restrict__ out)
{
    // Block identity: bid = ((b*NQ + q)*NMM + m)*4 + qt
    const int bid = blockIdx.x;
    const int qt  = bid & 3;                 // y-quarter of the 16x16 tile
    const int bqm = bid >> 2;
    const int m   = bqm % NMM;
    const int q   = (bqm / NMM) % NQ;
    const int b   = bqm / (NMM * NQ);
    const int qm  = q * NMM + m;

    // ---- Stage W' = collect_weights(coeffs) * F[qm] into LDS ----
    __shared__ float2 Wp[NIC][NNC][NOC];     // 25.6 KiB
    for (int idx = threadIdx.x; idx < NIC * NNC * NOC; idx += 256) {
        const int o = idx & (NOC - 1);
        const int n = (idx >> 4) % NNC;
        const int c = idx / (NOC * NNC);
        float wr, wi;
        if (n < 12) {
            wr = coeffs[(c * NNC + (23 - 2 * n)) * NOC + o];
            wi = coeffs[(c * NNC + (24 - 2 * n)) * NOC + o];
        } else if (n == 12) {
            wr = coeffs[(c * NNC + 0) * NOC + o];
            wi = 0.0f;
        } else {
            wr = coeffs[(c * NNC + (2 * n - 25)) * NOC + o];
            wi = coeffs[(c * NNC + (2 * n - 24)) * NOC + o];
        }
        const float fr = F_re[qm * NNC + n];
        const float fi = F_im[qm * NNC + n];
        Wp[c][n][o] = make_float2(wr * fr - wi * fi, wr * fi + wi * fr);
    }
    __syncthreads();

    // ---- Thread identity: og wave-uniform, p = point within quarter-tile ----
    const int tid = threadIdx.x;
    const int og  = tid >> 6;                // 0..3 (uniform per wave)
    const int p   = tid & 63;
    const int y   = qt * 4 + (p >> 4);
    const int x   = p & 15;

    // ---- Block-uniform basis parameters (uniform addresses -> scalar loads) ----
    const float pAre = pAlpha_re[qm], pAim = pAlpha_im[qm];
    const float pPre = pPhi_re[m],    pPim = pPhi_im[m];
    float pSre[NV], pSim[NV];
    #pragma unroll
    for (int v = 0; v < NV; ++v) { pSre[v] = pPsi_re[m * NV + v]; pSim[v] = pPsi_im[m * NV + v]; }

    const int pbase = ((b * NBB + y) * NBB + x) * NIC;

    float accr[OPG], acci[OPG];
    #pragma unroll
    for (int oo = 0; oo < OPG; ++oo) { accr[oo] = 0.0f; acci[oo] = 0.0f; }

    #pragma unroll 1
    for (int c = 0; c < NIC; ++c) {
        const float xr = x_re[pbase + c], xi = x_im[pbase + c];
        const float la = lnAlpha[pbase + c], ph = Phi[pbase + c];
        const float lt = lnTau[pbase + c],   ps = Psi[pbase + c];

        // A = x * exp(la*pAlpha + ph*pPhi)
        const float ar = la * pAre + ph * pPre;
        const float ai = la * pAim + ph * pPim;
        const float ea = __expf(ar);
        float sa, ca;
        __sincosf(ai, &sa, &ca);
        const float er_ = ea * ca, ei_ = ea * sa;
        const float Are = xr * er_ - xi * ei_;
        const float Aim = xr * ei_ + xi * er_;

        // ev[v] = exp(ps * pPsi[v])  (fully unrolled -> static indices -> regs)
        float evr[NV], evi[NV];
        #pragma unroll
        for (int v = 0; v < NV; ++v) {
            const float rr = __expf(ps * pSre[v]);
            float s, cc;
            __sincosf(ps * pSim[v], &s, &cc);
            evr[v] = rr * cc; evi[v] = rr * s;
        }

        // u-loop ROLLED: small code body (I-cache resident); eu computed in-loop
        #pragma unroll 1
        for (int u = 0; u < NU; ++u) {
            const float ptr_ = pTau_re[qm * NU + u];   // uniform -> s_load
            const float pti_ = pTau_im[qm * NU + u];
            const float ru = __expf(lt * ptr_);
            float su, cu;
            __sincosf(lt * pti_, &su, &cu);
            const float eur_ = ru * cu, eui_ = ru * su;
            const float gr = Are * eur_ - Aim * eui_;
            const float gi = Are * eui_ + Aim * eur_;
            #pragma unroll
            for (int v = 0; v < NV; ++v) {
                const float tr = gr * evr[v] - gi * evi[v];
                const float ti = gr * evi[v] + gi * evr[v];
                #pragma unroll
                for (int oo = 0; oo < OPG; ++oo) {
                    const float2 w = Wp[c][u * NV + v][og * OPG + oo];
                    accr[oo] += tr * w.x - ti * w.y;
                    acci[oo] += tr * w.y + ti * w.x;
                }
            }
        }
    }

    // ---- Write out: [b, o, q, m, y, x, 2] ----
    #pragma unroll
    for (int oo = 0; oo < OPG; ++oo) {
        const int o = og * OPG + oo;
        const size_t oi = (((((size_t)b * NOC + o) * NQ + q) * NMM + m) * NBB + y) * NBB + x;
        reinterpret_cast<float2*>(out)[oi] = make_float2(accr[oo], acci[oo]);
    }
}

extern "C" void kernel_launch(void* const* d_in, const int* in_sizes, int n_in,
                              void* d_out, int out_size, void* d_ws, size_t ws_size,
                              hipStream_t stream) {
    const float* x_re      = (const float*)d_in[0];
    const float* x_im      = (const float*)d_in[1];
    const float* lnAlpha   = (const float*)d_in[2];
    const float* Phi       = (const float*)d_in[3];
    const float* lnTau     = (const float*)d_in[4];
    const float* Psi       = (const float*)d_in[5];
    const float* pAlpha_re = (const float*)d_in[6];
    const float* pAlpha_im = (const float*)d_in[7];
    const float* pPhi_re   = (const float*)d_in[8];
    const float* pPhi_im   = (const float*)d_in[9];
    const float* pTau_re   = (const float*)d_in[10];
    const float* pTau_im   = (const float*)d_in[11];
    const float* pPsi_re   = (const float*)d_in[12];
    const float* pPsi_im   = (const float*)d_in[13];
    const float* F_re      = (const float*)d_in[14];
    const float* F_im      = (const float*)d_in[15];
    const float* coeffs    = (const float*)d_in[16];
    float* out = (float*)d_out;

    dim3 grid(NBATCH * NQ * NMM * 4);   // 1440: (b,q,m) x 4 quarter-tiles
    dim3 block(256);                    // 4 o-group waves x 64 points
    lbc_main<<<grid, block, 0, stream>>>(
        x_re, x_im, lnAlpha, Phi, lnTau, Psi,
        pAlpha_re, pAlpha_im, pPhi_re, pPhi_im,
        pTau_re, pTau_im, pPsi_re, pPsi_im,
        F_re, F_im, coeffs, out);
}

// Round 10
// 115.603 us; speedup vs baseline: 9.6442x; 1.4431x over previous
//
#include <hip/hip_runtime.h>
#include <hip/hip_bf16.h>

#define NBATCH 2
#define NBB    16
#define NIC    8
#define NOC    16
#define NQ     30
#define NMM    6
#define NU     5
#define NV     5
#define NNC    25   // NU*NV

typedef __attribute__((ext_vector_type(8))) short bf16x8;
typedef __attribute__((ext_vector_type(4))) float f32x4;

// pack two floats -> two bf16 (RNE) in one dword
__device__ __forceinline__ unsigned pk2(float a, float b) {
    unsigned ua = __builtin_bit_cast(unsigned, a);
    unsigned ub = __builtin_bit_cast(unsigned, b);
    ua += 0x7fffu + ((ua >> 16) & 1u);
    ub += 0x7fffu + ((ub >> 16) & 1u);
    return (ua >> 16) | (ub & 0xffff0000u);
}

__device__ __forceinline__ float2 wentry(const float* __restrict__ coeffs,
                                         int c, int n, int o) {
    if (n < 12)
        return make_float2(coeffs[(c * NNC + (23 - 2 * n)) * NOC + o],
                           coeffs[(c * NNC + (24 - 2 * n)) * NOC + o]);
    if (n == 12)
        return make_float2(coeffs[(c * NNC) * NOC + o], 0.0f);
    return make_float2(coeffs[(c * NNC + (2 * n - 25)) * NOC + o],
                       coeffs[(c * NNC + (2 * n - 24)) * NOC + o]);
}

// ---- T-build macros: all named scalars ----
#define EU_G(U)                                                          \
    const float ru##U = __expf(lt * pTau_re[qm * NU + U]);               \
    float su##U, cu##U;                                                  \
    __sincosf(lt * pTau_im[qm * NU + U], &su##U, &cu##U);                \
    const float g##U##r = Are * (ru##U * cu##U) - Aim * (ru##U * su##U); \
    const float g##U##i = Are * (ru##U * su##U) + Aim * (ru##U * cu##U);

#define EVV(V)                                                           \
    const float rv##V = __expf(ps * pPsi_re[m * NV + V]);                \
    float sv##V, cv##V;                                                  \
    __sincosf(ps * pPsi_im[m * NV + V], &sv##V, &cv##V);                 \
    const float e##V##r = rv##V * cv##V, e##V##i = rv##V * sv##V;

#define TAP(N, U, V)                                                     \
    const float tr##N = g##U##r * e##V##r - g##U##i * e##V##i;           \
    const float ti##N = g##U##r * e##V##i + g##U##i * e##V##r;

#define MT_MFMA(SUF, MT, CH, BWR, BWI) {                                 \
    const bf16x8 atr = *reinterpret_cast<const bf16x8*>(                 \
        &T_lds[(CH) * (128 * 36) + ((MT) * 16 + l15) * 36 + sl * 4]);    \
    const bf16x8 ati = *reinterpret_cast<const bf16x8*>(                 \
        &T_lds[(CH) * (128 * 36) + ((MT) * 16 + l15) * 36 + 16 + sl * 4]);\
    aRR##SUF = __builtin_amdgcn_mfma_f32_16x16x32_bf16(atr, BWR, aRR##SUF, 0, 0, 0); \
    aII##SUF = __builtin_amdgcn_mfma_f32_16x16x32_bf16(ati, BWI, aII##SUF, 0, 0, 0); \
    aRI##SUF = __builtin_amdgcn_mfma_f32_16x16x32_bf16(atr, BWI, aRI##SUF, 0, 0, 0); \
    aIR##SUF = __builtin_amdgcn_mfma_f32_16x16x32_bf16(ati, BWR, aIR##SUF, 0, 0, 0); }

__global__ __launch_bounds__(256, 3) void lbc_main(
    const float* __restrict__ x_re,   const float* __restrict__ x_im,
    const float* __restrict__ lnAlpha,const float* __restrict__ Phi,
    const float* __restrict__ lnTau,  const float* __restrict__ Psi,
    const float* __restrict__ pAlpha_re, const float* __restrict__ pAlpha_im,
    const float* __restrict__ pPhi_re,   const float* __restrict__ pPhi_im,
    const float* __restrict__ pTau_re,   const float* __restrict__ pTau_im,
    const float* __restrict__ pPsi_re,   const float* __restrict__ pPsi_im,
    const float* __restrict__ F_re,      const float* __restrict__ F_im,
    const float* __restrict__ coeffs,
    float* __restrict__ out)
{
    // T: [2 chunks][128 points][36 dwords] (Tr 16 dw, Ti 16 dw, 4 pad) = 36 KiB
    // W: [2 planes][8 c][64 lanes][4 dwords] B-frag order, bf16      = 16 KiB
    __shared__ unsigned T_lds[2 * 128 * 36];
    __shared__ unsigned W_lds[2 * NIC * 64 * 4];

    // Block identity: bid = ((b*NQ + q)*NMM + m)*2 + half
    const int bid  = blockIdx.x;
    const int half = bid & 1;
    const int rest = bid >> 1;
    const int m    = rest % NMM;
    const int q    = (rest / NMM) % NQ;
    const int b    = rest / (NMM * NQ);
    const int qm   = q * NMM + m;

    // ---- Stage W' = collect_weights * F  into B-fragment-ordered bf16 LDS ----
    for (int idx = threadIdx.x; idx < 2 * NIC * 64 * 4; idx += 256) {
        const int j  = idx & 3;
        const int l  = (idx >> 2) & 63;
        const int c  = (idx >> 8) & 7;
        const int pl = idx >> 11;            // 0 = real plane, 1 = imag plane
        const int o  = l & 15;
        const int k0 = (l >> 4) * 8 + 2 * j;
        float v0 = 0.f, v1 = 0.f;
        if (k0 < NNC) {
            const float2 w = wentry(coeffs, c, k0, o);
            const float fr = F_re[qm * NNC + k0], fi = F_im[qm * NNC + k0];
            v0 = pl ? (w.x * fi + w.y * fr) : (w.x * fr - w.y * fi);
        }
        if (k0 + 1 < NNC) {
            const float2 w = wentry(coeffs, c, k0 + 1, o);
            const float fr = F_re[qm * NNC + k0 + 1], fi = F_im[qm * NNC + k0 + 1];
            v1 = pl ? (w.x * fi + w.y * fr) : (w.x * fr - w.y * fi);
        }
        W_lds[idx] = pk2(v0, v1);
    }

    // ---- Thread identity ----
    const int tid = threadIdx.x;
    const int ptl = tid & 127;               // point within 128-row tile
    const int h   = tid >> 7;                // c-half (chunk producer id)
    const int y   = half * 8 + (ptl >> 4);
    const int x   = ptl & 15;
    const int pbase = ((b * NBB + y) * NBB + x) * NIC;

    const int l   = tid & 63;
    const int w   = tid >> 6;                // wave id 0..3
    const int l15 = l & 15;
    const int sl  = l >> 4;

    // uniform basis params for A-factor
    const float pAre = pAlpha_re[qm], pAim = pAlpha_im[qm];
    const float pPre = pPhi_re[m],    pPim = pPhi_im[m];

    f32x4 aRRa = {0.f, 0.f, 0.f, 0.f}, aIIa = {0.f, 0.f, 0.f, 0.f};
    f32x4 aRIa = {0.f, 0.f, 0.f, 0.f}, aIRa = {0.f, 0.f, 0.f, 0.f};
    f32x4 aRRb = {0.f, 0.f, 0.f, 0.f}, aIIb = {0.f, 0.f, 0.f, 0.f};
    f32x4 aRIb = {0.f, 0.f, 0.f, 0.f}, aIRb = {0.f, 0.f, 0.f, 0.f};

    __syncthreads();   // W staged

    #pragma unroll 1
    for (int s = 0; s < 4; ++s) {
        // ================= T-build: c = h*4 + s =================
        {
            const int c  = h * 4 + s;
            const int pc = pbase + c;
            const float xr = x_re[pc], xi = x_im[pc];
            const float la = lnAlpha[pc], ph = Phi[pc];
            const float lt = lnTau[pc],   ps = Psi[pc];

            const float ar = la * pAre + ph * pPre;
            const float ai = la * pAim + ph * pPim;
            const float ea = __expf(ar);
            float sa, ca;
            __sincosf(ai, &sa, &ca);
            const float er_ = ea * ca, ei_ = ea * sa;
            const float Are = xr * er_ - xi * ei_;
            const float Aim = xr * ei_ + xi * er_;

            EU_G(0) EU_G(1) EU_G(2) EU_G(3) EU_G(4)
            EVV(0) EVV(1) EVV(2) EVV(3) EVV(4)

            uint4* trow = reinterpret_cast<uint4*>(&T_lds[h * (128 * 36) + ptl * 36]);

            {   // taps 0..7
                TAP(0,0,0) TAP(1,0,1) TAP(2,0,2) TAP(3,0,3)
                TAP(4,0,4) TAP(5,1,0) TAP(6,1,1) TAP(7,1,2)
                trow[0] = make_uint4(pk2(tr0,tr1), pk2(tr2,tr3), pk2(tr4,tr5), pk2(tr6,tr7));
                trow[4] = make_uint4(pk2(ti0,ti1), pk2(ti2,ti3), pk2(ti4,ti5), pk2(ti6,ti7));
            }
            {   // taps 8..15
                TAP(8,1,3) TAP(9,1,4) TAP(10,2,0) TAP(11,2,1)
                TAP(12,2,2) TAP(13,2,3) TAP(14,2,4) TAP(15,3,0)
                trow[1] = make_uint4(pk2(tr8,tr9), pk2(tr10,tr11), pk2(tr12,tr13), pk2(tr14,tr15));
                trow[5] = make_uint4(pk2(ti8,ti9), pk2(ti10,ti11), pk2(ti12,ti13), pk2(ti14,ti15));
            }
            {   // taps 16..23
                TAP(16,3,1) TAP(17,3,2) TAP(18,3,3) TAP(19,3,4)
                TAP(20,4,0) TAP(21,4,1) TAP(22,4,2) TAP(23,4,3)
                trow[2] = make_uint4(pk2(tr16,tr17), pk2(tr18,tr19), pk2(tr20,tr21), pk2(tr22,tr23));
                trow[6] = make_uint4(pk2(ti16,ti17), pk2(ti18,ti19), pk2(ti20,ti21), pk2(ti22,ti23));
            }
            {   // tap 24 + zero pad
                TAP(24,4,4)
                trow[3] = make_uint4(pk2(tr24, 0.f), 0u, 0u, 0u);
                trow[7] = make_uint4(pk2(ti24, 0.f), 0u, 0u, 0u);
            }
        }
        __syncthreads();   // T ready

        // ================= MFMA: both chunks, 2 M-tiles per wave =================
        {
            const int c0 = s;                // chunk 0 tap-block
            const bf16x8 bwr0 = *reinterpret_cast<const bf16x8*>(&W_lds[((0 * NIC + c0) * 64 + l) * 4]);
            const bf16x8 bwi0 = *reinterpret_cast<const bf16x8*>(&W_lds[((1 * NIC + c0) * 64 + l) * 4]);
            MT_MFMA(a, 2 * w,     0, bwr0, bwi0)
            MT_MFMA(b, 2 * w + 1, 0, bwr0, bwi0)

            const int c1 = 4 + s;            // chunk 1 tap-block
            const bf16x8 bwr1 = *reinterpret_cast<const bf16x8*>(&W_lds[((0 * NIC + c1) * 64 + l) * 4]);
            const bf16x8 bwi1 = *reinterpret_cast<const bf16x8*>(&W_lds[((1 * NIC + c1) * 64 + l) * 4]);
            MT_MFMA(a, 2 * w,     1, bwr1, bwi1)
            MT_MFMA(b, 2 * w + 1, 1, bwr1, bwi1)
        }
        __syncthreads();   // safe to overwrite T
    }

    // ================= Epilogue: out[b,o,q,m,y,x,(re,im)] =================
    const int o = l15;
    const size_t plane = (((size_t)b * NOC + o) * NQ + q) * NMM + m;
    float4* const o4 = reinterpret_cast<float4*>(out);
    {
        const f32x4 vr = aRRa - aIIa;
        const f32x4 vi = aRIa + aIRa;
        const size_t base2 = plane * 256 + half * 128 + (2 * w) * 16 + sl * 4;
        o4[(base2 >> 1)]     = make_float4(vr.x, vi.x, vr.y, vi.y);
        o4[(base2 >> 1) + 1] = make_float4(vr.z, vi.z, vr.w, vi.w);
    }
    {
        const f32x4 vr = aRRb - aIIb;
        const f32x4 vi = aRIb + aIRb;
        const size_t base2 = plane * 256 + half * 128 + (2 * w + 1) * 16 + sl * 4;
        o4[(base2 >> 1)]     = make_float4(vr.x, vi.x, vr.y, vi.y);
        o4[(base2 >> 1) + 1] = make_float4(vr.z, vi.z, vr.w, vi.w);
    }
}

extern "C" void kernel_launch(void* const* d_in, const int* in_sizes, int n_in,
                              void* d_out, int out_size, void* d_ws, size_t ws_size,
                              hipStream_t stream) {
    const float* x_re      = (const float*)d_in[0];
    const float* x_im      = (const float*)d_in[1];
    const float* lnAlpha   = (const float*)d_in[2];
    const float* Phi       = (const float*)d_in[3];
    const float* lnTau     = (const float*)d_in[4];
    const float* Psi       = (const float*)d_in[5];
    const float* pAlpha_re = (const float*)d_in[6];
    const float* pAlpha_im = (const float*)d_in[7];
    const float* pPhi_re   = (const float*)d_in[8];
    const float* pPhi_im   = (const float*)d_in[9];
    const float* pTau_re   = (const float*)d_in[10];
    const float* pTau_im   = (const float*)d_in[11];
    const float* pPsi_re   = (const float*)d_in[12];
    const float* pPsi_im   = (const float*)d_in[13];
    const float* F_re      = (const float*)d_in[14];
    const float* F_im      = (const float*)d_in[15];
    const float* coeffs    = (const float*)d_in[16];
    float* out = (float*)d_out;

    dim3 grid(NBATCH * NQ * NMM * 2);   // 720: (b,q,m) x 2 half-tiles
    dim3 block(256);                    // 128 points x 2 c-halves = 4 waves
    lbc_main<<<grid, block, 0, stream>>>(
        x_re, x_im, lnAlpha, Phi, lnTau, Psi,
        pAlpha_re, pAlpha_im, pPhi_re, pPhi_im,
        pTau_re, pTau_im, pPsi_re, pPsi_im,
        F_re, F_im, coeffs, out);
}

// Round 13
// 110.057 us; speedup vs baseline: 10.1302x; 1.0504x over previous
//
#include <hip/hip_runtime.h>
#include <hip/hip_bf16.h>

#define NBATCH 2
#define NBB    16
#define NIC    8
#define NOC    16
#define NQ     30
#define NMM    6
#define NU     5
#define NV     5
#define NNC    25   // NU*NV

typedef __attribute__((ext_vector_type(8))) short bf16x8;
typedef __attribute__((ext_vector_type(4))) float f32x4;

// pack two floats -> two bf16 (manual RNE — proven in R10; do NOT use
// (__bf16) casts here: suspected RTZ lowering biased the K=200 accumulation)
__device__ __forceinline__ unsigned pk2(float a, float b) {
    unsigned ua = __builtin_bit_cast(unsigned, a);
    unsigned ub = __builtin_bit_cast(unsigned, b);
    ua += 0x7fffu + ((ua >> 16) & 1u);
    ub += 0x7fffu + ((ub >> 16) & 1u);
    return (ua >> 16) | (ub & 0xffff0000u);
}

__device__ __forceinline__ float2 wentry(const float* __restrict__ coeffs,
                                         int c, int n, int o) {
    if (n < 12)
        return make_float2(coeffs[(c * NNC + (23 - 2 * n)) * NOC + o],
                           coeffs[(c * NNC + (24 - 2 * n)) * NOC + o]);
    if (n == 12)
        return make_float2(coeffs[(c * NNC) * NOC + o], 0.0f);
    return make_float2(coeffs[(c * NNC + (2 * n - 25)) * NOC + o],
                       coeffs[(c * NNC + (2 * n - 24)) * NOC + o]);
}

// ---- T-build macros: all named scalars; params pre-hoisted ----
#define EU_G(U)                                                          \
    const float ru##U = __expf(lt * pTr##U);                             \
    float su##U, cu##U;                                                  \
    __sincosf(lt * pTi##U, &su##U, &cu##U);                              \
    const float g##U##r = Are * (ru##U * cu##U) - Aim * (ru##U * su##U); \
    const float g##U##i = Are * (ru##U * su##U) + Aim * (ru##U * cu##U);

#define EVV(V)                                                           \
    const float rv##V = __expf(ps * pSr##V);                             \
    float sv##V, cv##V;                                                  \
    __sincosf(ps * pSi##V, &sv##V, &cv##V);                              \
    const float e##V##r = rv##V * cv##V, e##V##i = rv##V * sv##V;

#define TAP(N, U, V)                                                     \
    const float tr##N = g##U##r * e##V##r - g##U##i * e##V##i;           \
    const float ti##N = g##U##r * e##V##i + g##U##i * e##V##r;

// full T-build for one channel; writes this thread's row of T_lds
#define TBUILD(XR, XI, LA, PH, LT, PS) {                                 \
    const float xr = (XR), xi = (XI), la = (LA);                         \
    const float ph = (PH), lt = (LT), ps = (PS);                         \
    const float ar = la * pAre + ph * pPre;                              \
    const float ai = la * pAim + ph * pPim;                              \
    const float ea = __expf(ar);                                         \
    float sa, ca;                                                        \
    __sincosf(ai, &sa, &ca);                                             \
    const float er_ = ea * ca, ei_ = ea * sa;                            \
    const float Are = xr * er_ - xi * ei_;                               \
    const float Aim = xr * ei_ + xi * er_;                               \
    EU_G(0) EU_G(1) EU_G(2) EU_G(3) EU_G(4)                              \
    EVV(0) EVV(1) EVV(2) EVV(3) EVV(4)                                   \
    uint4* trow = reinterpret_cast<uint4*>(&T_lds[h * (128 * 36) + ptl * 36]); \
    {   TAP(0,0,0) TAP(1,0,1) TAP(2,0,2) TAP(3,0,3)                      \
        TAP(4,0,4) TAP(5,1,0) TAP(6,1,1) TAP(7,1,2)                      \
        trow[0] = make_uint4(pk2(tr0,tr1), pk2(tr2,tr3), pk2(tr4,tr5), pk2(tr6,tr7));   \
        trow[4] = make_uint4(pk2(ti0,ti1), pk2(ti2,ti3), pk2(ti4,ti5), pk2(ti6,ti7)); } \
    {   TAP(8,1,3) TAP(9,1,4) TAP(10,2,0) TAP(11,2,1)                    \
        TAP(12,2,2) TAP(13,2,3) TAP(14,2,4) TAP(15,3,0)                  \
        trow[1] = make_uint4(pk2(tr8,tr9), pk2(tr10,tr11), pk2(tr12,tr13), pk2(tr14,tr15)); \
        trow[5] = make_uint4(pk2(ti8,ti9), pk2(ti10,ti11), pk2(ti12,ti13), pk2(ti14,ti15)); } \
    {   TAP(16,3,1) TAP(17,3,2) TAP(18,3,3) TAP(19,3,4)                  \
        TAP(20,4,0) TAP(21,4,1) TAP(22,4,2) TAP(23,4,3)                  \
        trow[2] = make_uint4(pk2(tr16,tr17), pk2(tr18,tr19), pk2(tr20,tr21), pk2(tr22,tr23)); \
        trow[6] = make_uint4(pk2(ti16,ti17), pk2(ti18,ti19), pk2(ti20,ti21), pk2(ti22,ti23)); } \
    {   TAP(24,4,4)                                                      \
        trow[3] = make_uint4(pk2(tr24, 0.f), 0u, 0u, 0u);                \
        trow[7] = make_uint4(pk2(ti24, 0.f), 0u, 0u, 0u); } }

#define MT_MFMA(SUF, MT, CH, BWR, BWI) {                                 \
    const bf16x8 atr = *reinterpret_cast<const bf16x8*>(                 \
        &T_lds[(CH) * (128 * 36) + ((MT) * 16 + l15) * 36 + sl * 4]);    \
    const bf16x8 ati = *reinterpret_cast<const bf16x8*>(                 \
        &T_lds[(CH) * (128 * 36) + ((MT) * 16 + l15) * 36 + 16 + sl * 4]);\
    aRR##SUF = __builtin_amdgcn_mfma_f32_16x16x32_bf16(atr, BWR, aRR##SUF, 0, 0, 0); \
    aII##SUF = __builtin_amdgcn_mfma_f32_16x16x32_bf16(ati, BWI, aII##SUF, 0, 0, 0); \
    aRI##SUF = __builtin_amdgcn_mfma_f32_16x16x32_bf16(atr, BWI, aRI##SUF, 0, 0, 0); \
    aIR##SUF = __builtin_amdgcn_mfma_f32_16x16x32_bf16(ati, BWR, aIR##SUF, 0, 0, 0); }

__global__ __launch_bounds__(256, 3) void lbc_main(
    const float* __restrict__ x_re,   const float* __restrict__ x_im,
    const float* __restrict__ lnAlpha,const float* __restrict__ Phi,
    const float* __restrict__ lnTau,  const float* __restrict__ Psi,
    const float* __restrict__ pAlpha_re, const float* __restrict__ pAlpha_im,
    const float* __restrict__ pPhi_re,   const float* __restrict__ pPhi_im,
    const float* __restrict__ pTau_re,   const float* __restrict__ pTau_im,
    const float* __restrict__ pPsi_re,   const float* __restrict__ pPsi_im,
    const float* __restrict__ F_re,      const float* __restrict__ F_im,
    const float* __restrict__ coeffs,
    float* __restrict__ out)
{
    __shared__ unsigned T_lds[2 * 128 * 36];        // 36.9 KiB
    __shared__ unsigned W_lds[2 * NIC * 64 * 4];    // 16 KiB

    const int bid  = blockIdx.x;
    const int half = bid & 1;
    const int rest = bid >> 1;
    const int m    = rest % NMM;
    const int q    = (rest / NMM) % NQ;
    const int b    = rest / (NMM * NQ);
    const int qm   = q * NMM + m;

    // ---- Thread identity ----
    const int tid = threadIdx.x;
    const int ptl = tid & 127;
    const int h   = tid >> 7;
    const int y   = half * 8 + (ptl >> 4);
    const int x   = ptl & 15;
    const int pt  = (b * NBB + y) * NBB + x;

    const int l   = tid & 63;
    const int w   = tid >> 6;
    const int l15 = l & 15;
    const int sl  = l >> 4;

    // ---- Hoisted inputs: this thread's 4 channels = one float4 per array ----
    const int p4 = pt * 2 + h;                      // float4 index
    const float4 xr4 = reinterpret_cast<const float4*>(x_re)[p4];
    const float4 xi4 = reinterpret_cast<const float4*>(x_im)[p4];
    const float4 la4 = reinterpret_cast<const float4*>(lnAlpha)[p4];
    const float4 ph4 = reinterpret_cast<const float4*>(Phi)[p4];
    const float4 lt4 = reinterpret_cast<const float4*>(lnTau)[p4];
    const float4 ps4 = reinterpret_cast<const float4*>(Psi)[p4];

    // ---- Hoisted uniform basis params (SGPRs, loop-invariant) ----
    const float pAre = pAlpha_re[qm], pAim = pAlpha_im[qm];
    const float pPre = pPhi_re[m],    pPim = pPhi_im[m];
    const float pTr0 = pTau_re[qm*NU+0], pTi0 = pTau_im[qm*NU+0];
    const float pTr1 = pTau_re[qm*NU+1], pTi1 = pTau_im[qm*NU+1];
    const float pTr2 = pTau_re[qm*NU+2], pTi2 = pTau_im[qm*NU+2];
    const float pTr3 = pTau_re[qm*NU+3], pTi3 = pTau_im[qm*NU+3];
    const float pTr4 = pTau_re[qm*NU+4], pTi4 = pTau_im[qm*NU+4];
    const float pSr0 = pPsi_re[m*NV+0],  pSi0 = pPsi_im[m*NV+0];
    const float pSr1 = pPsi_re[m*NV+1],  pSi1 = pPsi_im[m*NV+1];
    const float pSr2 = pPsi_re[m*NV+2],  pSi2 = pPsi_im[m*NV+2];
    const float pSr3 = pPsi_re[m*NV+3],  pSi3 = pPsi_im[m*NV+3];
    const float pSr4 = pPsi_re[m*NV+4],  pSi4 = pPsi_im[m*NV+4];

    // ---- Prologue: build T(0) (c = h*4) while W-staging loads are in flight ----
    TBUILD(xr4.x, xi4.x, la4.x, ph4.x, lt4.x, ps4.x)

    // ---- Stage W' = collect_weights * F into B-fragment-ordered bf16 LDS ----
    for (int idx = threadIdx.x; idx < 2 * NIC * 64 * 4; idx += 256) {
        const int j  = idx & 3;
        const int ll = (idx >> 2) & 63;
        const int c  = (idx >> 8) & 7;
        const int pl = idx >> 11;
        const int o  = ll & 15;
        const int k0 = (ll >> 4) * 8 + 2 * j;
        float v0 = 0.f, v1 = 0.f;
        if (k0 < NNC) {
            const float2 wv = wentry(coeffs, c, k0, o);
            const float fr = F_re[qm * NNC + k0], fi = F_im[qm * NNC + k0];
            v0 = pl ? (wv.x * fi + wv.y * fr) : (wv.x * fr - wv.y * fi);
        }
        if (k0 + 1 < NNC) {
            const float2 wv = wentry(coeffs, c, k0 + 1, o);
            const float fr = F_re[qm * NNC + k0 + 1], fi = F_im[qm * NNC + k0 + 1];
            v1 = pl ? (wv.x * fi + wv.y * fr) : (wv.x * fr - wv.y * fi);
        }
        W_lds[idx] = pk2(v0, v1);
    }

    f32x4 aRRa = {0.f,0.f,0.f,0.f}, aIIa = {0.f,0.f,0.f,0.f};
    f32x4 aRIa = {0.f,0.f,0.f,0.f}, aIRa = {0.f,0.f,0.f,0.f};
    f32x4 aRRb = {0.f,0.f,0.f,0.f}, aIIb = {0.f,0.f,0.f,0.f};
    f32x4 aRIb = {0.f,0.f,0.f,0.f}, aIRb = {0.f,0.f,0.f,0.f};

    __syncthreads();   // W + T(0) staged

    #pragma unroll 1
    for (int s = 0; s < 4; ++s) {
        // ---- MFMA(s): chunks c0 = s, c1 = 4+s ----
        {
            const bf16x8 bwr0 = *reinterpret_cast<const bf16x8*>(&W_lds[((0 * NIC + s) * 64 + l) * 4]);
            const bf16x8 bwi0 = *reinterpret_cast<const bf16x8*>(&W_lds[((1 * NIC + s) * 64 + l) * 4]);
            MT_MFMA(a, 2 * w,     0, bwr0, bwi0)
            MT_MFMA(b, 2 * w + 1, 0, bwr0, bwi0)
            const bf16x8 bwr1 = *reinterpret_cast<const bf16x8*>(&W_lds[((0 * NIC + 4 + s) * 64 + l) * 4]);
            const bf16x8 bwi1 = *reinterpret_cast<const bf16x8*>(&W_lds[((1 * NIC + 4 + s) * 64 + l) * 4]);
            MT_MFMA(a, 2 * w,     1, bwr1, bwi1)
            MT_MFMA(b, 2 * w + 1, 1, bwr1, bwi1)
        }
        if (s < 3) {
            __syncthreads();   // T(s) fully consumed
            // uniform (scalar) channel select: component s+1 of hoisted float4s
            const float nxr = s == 0 ? xr4.y : (s == 1 ? xr4.z : xr4.w);
            const float nxi = s == 0 ? xi4.y : (s == 1 ? xi4.z : xi4.w);
            const float nla = s == 0 ? la4.y : (s == 1 ? la4.z : la4.w);
            const float nph = s == 0 ? ph4.y : (s == 1 ? ph4.z : ph4.w);
            const float nlt = s == 0 ? lt4.y : (s == 1 ? lt4.z : lt4.w);
            const float nps = s == 0 ? ps4.y : (s == 1 ? ps4.z : ps4.w);
            TBUILD(nxr, nxi, nla, nph, nlt, nps)
            __syncthreads();   // T(s+1) ready
        }
    }

    // ---- Epilogue: out[b,o,q,m,y,x,(re,im)] ----
    const int o = l15;
    const size_t plane = (((size_t)b * NOC + o) * NQ + q) * NMM + m;
    float4* const o4 = reinterpret_cast<float4*>(out);
    {
        const f32x4 vr = aRRa - aIIa;
        const f32x4 vi = aRIa + aIRa;
        const size_t base2 = plane * 256 + half * 128 + (2 * w) * 16 + sl * 4;
        o4[(base2 >> 1)]     = make_float4(vr.x, vi.x, vr.y, vi.y);
        o4[(base2 >> 1) + 1] = make_float4(vr.z, vi.z, vr.w, vi.w);
    }
    {
        const f32x4 vr = aRRb - aIIb;
        const f32x4 vi = aRIb + aIRb;
        const size_t base2 = plane * 256 + half * 128 + (2 * w + 1) * 16 + sl * 4;
        o4[(base2 >> 1)]     = make_float4(vr.x, vi.x, vr.y, vi.y);
        o4[(base2 >> 1) + 1] = make_float4(vr.z, vi.z, vr.w, vi.w);
    }
}

extern "C" void kernel_launch(void* const* d_in, const int* in_sizes, int n_in,
                              void* d_out, int out_size, void* d_ws, size_t ws_size,
                              hipStream_t stream) {
    const float* x_re      = (const float*)d_in[0];
    const float* x_im      = (const float*)d_in[1];
    const float* lnAlpha   = (const float*)d_in[2];
    const float* Phi       = (const float*)d_in[3];
    const float* lnTau     = (const float*)d_in[4];
    const float* Psi       = (const float*)d_in[5];
    const float* pAlpha_re = (const float*)d_in[6];
    const float* pAlpha_im = (const float*)d_in[7];
    const float* pPhi_re   = (const float*)d_in[8];
    const float* pPhi_im   = (const float*)d_in[9];
    const float* pTau_re   = (const float*)d_in[10];
    const float* pTau_im   = (const float*)d_in[11];
    const float* pPsi_re   = (const float*)d_in[12];
    const float* pPsi_im   = (const float*)d_in[13];
    const float* F_re      = (const float*)d_in[14];
    const float* F_im      = (const float*)d_in[15];
    const float* coeffs    = (const float*)d_in[16];
    float* out = (float*)d_out;

    dim3 grid(NBATCH * NQ * NMM * 2);   // 720: (b,q,m) x 2 half-tiles
    dim3 block(256);                    // 128 points x 2 c-halves = 4 waves
    lbc_main<<<grid, block, 0, stream>>>(
        x_re, x_im, lnAlpha, Phi, lnTau, Psi,
        pAlpha_re, pAlpha_im, pPhi_re, pPhi_im,
        pTau_re, pTau_im, pPsi_re, pPsi_im,
        F_re, F_im, coeffs, out);
}